// Round 3
// baseline (21483.827 us; speedup 1.0000x reference)
//
#include <hip/hip_runtime.h>
#include <stdint.h>

// ---------------------------------------------------------------------------
// ODE-RNN encoder, f32 I/O (per reference dtypes), bf16 MFMA internals.
// rk4_solve(h_obs) is independent per (t,b) row -> ODE phase is one batched
// row-local megakernel (M=65536, 32 rows/block, full 512-wide LN in-block).
// Only the GRU h_prev chain is sequential (64 fused launches).
// Defensive round: no async staging, single-buffered, barrier-bracketed,
// static LDS kept under 64 KB per kernel.
// ---------------------------------------------------------------------------

typedef __bf16 bf16x8 __attribute__((ext_vector_type(8)));
typedef float floatx4 __attribute__((ext_vector_type(4)));

#define AP 520  // padded A row (ushorts): 1040 B, 16B-aligned
#define BP 40   // padded B row (ushorts): 80 B, 16B-aligned

static __device__ __forceinline__ float bf2f(unsigned short u) {
  union { unsigned int u32; float f; } c;
  c.u32 = ((unsigned int)u) << 16;
  return c.f;
}
static __device__ __forceinline__ unsigned short f2bf(float f) {
  union { __bf16 h; unsigned short u; } c;
  c.h = (__bf16)f;  // RNE hardware convert
  return c.u;
}
// column owned by (wave, ni, ml): halves interleaved so all 8 waves work in both halves
static __device__ __forceinline__ int ncol(int wv, int ni, int ml) {
  return 256 * (ni >> 1) + 32 * wv + 16 * (ni & 1) + ml;
}

// ---------------------------------------------------------------------------
// transpose + f32->bf16 convert: dst[c][r] = (bf16)src[r][c]
// ---------------------------------------------------------------------------
__global__ void transpose_f2b(const float* __restrict__ src, unsigned short* __restrict__ dst,
                              int R, int C) {
  __shared__ float t[32][33];
  int c0 = blockIdx.x * 32, r0 = blockIdx.y * 32;
  int tx = threadIdx.x, ty = threadIdx.y;  // 32 x 8
#pragma unroll
  for (int i = 0; i < 32; i += 8) t[ty + i][tx] = src[(size_t)(r0 + ty + i) * C + c0 + tx];
  __syncthreads();
#pragma unroll
  for (int i = 0; i < 32; i += 8) dst[(size_t)(c0 + ty + i) * R + r0 + tx] = f2bf(t[tx][ty + i]);
}

// ---------------------------------------------------------------------------
// obs embed: y = leaky(LN(xs @ W + b)) (f32 in, bf16 out), one wave per row
// ---------------------------------------------------------------------------
__global__ __launch_bounds__(256) void obs_embed(
    const float* __restrict__ xs, const float* __restrict__ W,
    const float* __restrict__ bias, const float* __restrict__ gam,
    const float* __restrict__ bet, unsigned short* __restrict__ Y) {
  __shared__ float Wl[4096];
  const int tid = threadIdx.x, lane = tid & 63, wv = tid >> 6;
#pragma unroll
  for (int i = 0; i < 16; ++i) Wl[i * 256 + tid] = W[i * 256 + tid];
  __syncthreads();
  size_t row = (size_t)blockIdx.x * 4 + wv;
  float xf[8];
  {
    const float* xp = xs + row * 8;
#pragma unroll
    for (int k = 0; k < 8; ++k) xf[k] = xp[k];
  }
  int n0 = lane * 8;
  float a[8];
#pragma unroll
  for (int j = 0; j < 8; ++j) a[j] = bias[n0 + j];
#pragma unroll
  for (int k = 0; k < 8; ++k)
#pragma unroll
    for (int j = 0; j < 8; ++j) a[j] += xf[k] * Wl[k * 512 + n0 + j];
  float s1 = 0.f, s2 = 0.f;
#pragma unroll
  for (int j = 0; j < 8; ++j) { s1 += a[j]; s2 += a[j] * a[j]; }
#pragma unroll
  for (int off = 1; off < 64; off <<= 1) { s1 += __shfl_xor(s1, off); s2 += __shfl_xor(s2, off); }
  float mean = s1 * (1.f / 512.f);
  float rstd = rsqrtf(s2 * (1.f / 512.f) - mean * mean + 1e-5f);
  unsigned short o[8] __attribute__((aligned(16)));
#pragma unroll
  for (int j = 0; j < 8; ++j) {
    float v = (a[j] - mean) * rstd * gam[n0 + j] + bet[n0 + j];
    v = v > 0.f ? v : 0.01f * v;
    o[j] = f2bf(v);
  }
  *(uint4*)(Y + row * 512 + n0) = *(const uint4*)o;
}

// ---------------------------------------------------------------------------
// ODE megakernel. A-tile (32 x 512, padded) resident in LDS; B streams through
// one 256x32 window, N processed in two halves. All phases barrier-bracketed.
// ---------------------------------------------------------------------------
static __device__ __forceinline__ void gemm32(const unsigned short* __restrict__ Bt,
                                              const unsigned short* As, unsigned short* Bs,
                                              int tid, int wv, int lane, floatx4 (&acc)[2][4]) {
  const int ml = lane & 15, qd = lane >> 4;
#pragma unroll
  for (int mi = 0; mi < 2; ++mi)
#pragma unroll
    for (int ni = 0; ni < 4; ++ni) acc[mi][ni] = 0.f;
  for (int half = 0; half < 2; ++half) {
    for (int kk = 0; kk < 16; ++kk) {
      __syncthreads();  // previous Bs reads (and epilogue As writes) done
#pragma unroll
      for (int c = 0; c < 2; ++c) {
        int id = c * 512 + tid;  // 0..1023 chunks of 8 bf16
        int r = id >> 2, kc = id & 3;
        uint4 v = *(const uint4*)(Bt + (size_t)(half * 256 + r) * 512 + kk * 32 + kc * 8);
        *(uint4*)(Bs + r * BP + kc * 8) = v;
      }
      __syncthreads();  // staging visible
      bf16x8 a[2], b[2];
#pragma unroll
      for (int mi = 0; mi < 2; ++mi)
        a[mi] = *(const bf16x8*)&As[(16 * mi + ml) * AP + kk * 32 + qd * 8];
#pragma unroll
      for (int nl = 0; nl < 2; ++nl)
        b[nl] = *(const bf16x8*)&Bs[(32 * wv + 16 * nl + ml) * BP + qd * 8];
#pragma unroll
      for (int mi = 0; mi < 2; ++mi)
#pragma unroll
        for (int nl = 0; nl < 2; ++nl)
          acc[mi][2 * half + nl] =
              __builtin_amdgcn_mfma_f32_16x16x32_bf16(a[mi], b[nl], acc[mi][2 * half + nl], 0, 0, 0);
    }
  }
}

// LN + leaky epilogue; writes bf16 result back into As (next layer's A).
static __device__ __forceinline__ void ln_epi32(floatx4 (&acc)[2][4], unsigned short* As,
                                                const float (&bv)[4], const float (&gv)[4],
                                                const float (&bev)[4], int wv, int lane, int tid,
                                                float* red, float* stat) {
  const int ml = lane & 15, qd = lane >> 4;
#pragma unroll
  for (int ni = 0; ni < 4; ++ni)
#pragma unroll
    for (int mi = 0; mi < 2; ++mi)
#pragma unroll
      for (int r = 0; r < 4; ++r) acc[mi][ni][r] += bv[ni];
#pragma unroll
  for (int mi = 0; mi < 2; ++mi)
#pragma unroll
    for (int r = 0; r < 4; ++r) {
      float s1 = 0.f, s2 = 0.f;
#pragma unroll
      for (int ni = 0; ni < 4; ++ni) { float x = acc[mi][ni][r]; s1 += x; s2 += x * x; }
#pragma unroll
      for (int off = 1; off < 16; off <<= 1) { s1 += __shfl_xor(s1, off); s2 += __shfl_xor(s2, off); }
      if (ml == 0) {
        int row = 16 * mi + 4 * qd + r;
        red[(row * 8 + wv) * 2 + 0] = s1;
        red[(row * 8 + wv) * 2 + 1] = s2;
      }
    }
  __syncthreads();
  if (tid < 32) {
    float S1 = 0.f, S2 = 0.f;
#pragma unroll
    for (int w = 0; w < 8; ++w) { S1 += red[(tid * 8 + w) * 2]; S2 += red[(tid * 8 + w) * 2 + 1]; }
    float mean = S1 * (1.f / 512.f);
    float var = S2 * (1.f / 512.f) - mean * mean;
    stat[tid * 2] = mean;
    stat[tid * 2 + 1] = rsqrtf(var + 1e-5f);
  }
  __syncthreads();
#pragma unroll
  for (int mi = 0; mi < 2; ++mi)
#pragma unroll
    for (int r = 0; r < 4; ++r) {
      int row = 16 * mi + 4 * qd + r;
      float mean = stat[row * 2], rstd = stat[row * 2 + 1];
#pragma unroll
      for (int ni = 0; ni < 4; ++ni) {
        float x = (acc[mi][ni][r] - mean) * rstd * gv[ni] + bev[ni];
        x = x > 0.f ? x : 0.01f * x;
        As[row * AP + ncol(wv, ni, ml)] = f2bf(x);
      }
    }
  __syncthreads();  // As writes visible before anyone reads
}

// RK4 stage combine: k = acc + bout; update h / ksum (fp32 regs, C-layout),
// write next stage input y into As.
static __device__ __forceinline__ void stage_epi32(floatx4 (&acc)[2][4], float (&h)[2][4][4],
                                                   float (&ks)[2][4][4], unsigned short* As,
                                                   const float (&bv)[4], int stg, int wv,
                                                   int lane) {
  const int ml = lane & 15, qd = lane >> 4;
  __syncthreads();  // all waves done reading As before overwrite
#pragma unroll
  for (int mi = 0; mi < 2; ++mi)
#pragma unroll
    for (int ni = 0; ni < 4; ++ni) {
      int n = ncol(wv, ni, ml);
#pragma unroll
      for (int r = 0; r < 4; ++r) {
        float kv = acc[mi][ni][r] + bv[ni];
        float y;
        if (stg == 0)      { ks[mi][ni][r] = kv;        y = h[mi][ni][r] + 0.125f * kv; }
        else if (stg == 1) { ks[mi][ni][r] += 2.f * kv; y = h[mi][ni][r] + 0.125f * kv; }
        else if (stg == 2) { ks[mi][ni][r] += 2.f * kv; y = h[mi][ni][r] + 0.25f * kv; }
        else {
          h[mi][ni][r] += (1.f / 24.f) * (ks[mi][ni][r] + kv);  // dt/6, dt=0.25
          y = h[mi][ni][r];
        }
        As[(16 * mi + 4 * qd + r) * AP + n] = f2bf(y);
      }
    }
  __syncthreads();  // As writes visible
}

__global__ __launch_bounds__(512) void ode_mega(
    const unsigned short* Y, const unsigned short* __restrict__ W1t,
    const unsigned short* __restrict__ W2t, const unsigned short* __restrict__ Wot,
    const float* __restrict__ b1, const float* __restrict__ tr, const float* __restrict__ g1,
    const float* __restrict__ be1, const float* __restrict__ b2, const float* __restrict__ g2,
    const float* __restrict__ be2, const float* __restrict__ bo, unsigned short* Yout) {
  __shared__ __align__(16) unsigned short As[32 * AP];  // 33280 B
  __shared__ __align__(16) unsigned short Bs[256 * BP]; // 20480 B
  __shared__ float red[512];                            // 2048 B
  __shared__ float stat[64];                            // 256 B   -> ~56 KB total

  const int tid = threadIdx.x;
  const int lane = tid & 63;
  const int wv = tid >> 6;
  const int ml = lane & 15;
  const int qd = lane >> 4;
  const size_t m0 = (size_t)blockIdx.x * 32;

  // per-lane param registers (fp32): {b1, time-row, g1, be1, b2, g2, be2, bout}
  float pv[8][4];
  {
    const float* srcs[8] = {b1, tr, g1, be1, b2, g2, be2, bo};
#pragma unroll
    for (int v = 0; v < 8; ++v)
#pragma unroll
      for (int ni = 0; ni < 4; ++ni) pv[v][ni] = srcs[v][ncol(wv, ni, ml)];
  }

  // stage initial A (y0 = obs embedding): 2048 chunks of 8 bf16 over 512 threads
#pragma unroll
  for (int c = 0; c < 4; ++c) {
    int id = c * 512 + tid;
    int r = id >> 6, kc = id & 63;
    uint4 v = *(const uint4*)(Y + (m0 + r) * 512 + kc * 8);
    *(uint4*)(As + r * AP + kc * 8) = v;
  }
  __syncthreads();

  float h[2][4][4];   // fp32 ODE state, MFMA C-layout
  float ks[2][4][4];  // fp32 RK4 ksum
#pragma unroll
  for (int mi = 0; mi < 2; ++mi)
#pragma unroll
    for (int ni = 0; ni < 4; ++ni)
#pragma unroll
      for (int r = 0; r < 4; ++r) {
        ks[mi][ni][r] = 0.f;
        h[mi][ni][r] = bf2f(As[(16 * mi + 4 * qd + r) * AP + ncol(wv, ni, ml)]);
      }

  for (int e = 0; e < 16; ++e) {  // 4 RK4 steps x 4 stages
    int stg = e & 3;
    float tval = 0.25f * (float)(e >> 2) + ((stg == 3) ? 0.25f : (stg ? 0.125f : 0.f));
    floatx4 acc[2][4];
    gemm32(W1t, As, Bs, tid, wv, lane, acc);
    {
      float bv[4];
#pragma unroll
      for (int ni = 0; ni < 4; ++ni) bv[ni] = pv[0][ni] + tval * pv[1][ni];  // fold t-concat
      ln_epi32(acc, As, bv, pv[2], pv[3], wv, lane, tid, red, stat);
    }
    gemm32(W2t, As, Bs, tid, wv, lane, acc);
    ln_epi32(acc, As, pv[4], pv[5], pv[6], wv, lane, tid, red, stat);
    gemm32(Wot, As, Bs, tid, wv, lane, acc);
    stage_epi32(acc, h, ks, As, pv[7], stg, wv, lane);
  }

  // write final h_ode (bf16) for the GRU phase
#pragma unroll
  for (int mi = 0; mi < 2; ++mi)
#pragma unroll
    for (int ni = 0; ni < 4; ++ni)
#pragma unroll
      for (int r = 0; r < 4; ++r) {
        size_t row = m0 + 16 * mi + 4 * qd + r;
        Yout[row * 512 + ncol(wv, ni, ml)] = f2bf(h[mi][ni][r]);
      }
}

// ---------------------------------------------------------------------------
// GRU step: gi = y_t @ W_ih, gh = h_prev @ W_hh, gates, h update (h fp32).
// grid (32, 8): 32 rows x 64 gate-cols per block, 4 waves.
// ---------------------------------------------------------------------------
__global__ __launch_bounds__(256) void gru_step(
    const unsigned short* __restrict__ Yt, const float* __restrict__ hprev,
    float* __restrict__ hnew, const unsigned short* __restrict__ Wiht,
    const unsigned short* __restrict__ Whht, const float* __restrict__ bih,
    const float* __restrict__ bhh) {
  __shared__ __align__(16) unsigned short Ay[32 * BP];      // 2560 B
  __shared__ __align__(16) unsigned short Ah[32 * BP];      // 2560 B
  __shared__ __align__(16) unsigned short Bg[6 * 64 * BP];  // 30720 B
  const int tid = threadIdx.x, lane = tid & 63, wv = tid >> 6;
  const int ml = lane & 15, qd = lane >> 4;
  const int m0 = blockIdx.x * 32;
  const int j0 = blockIdx.y * 64;

  floatx4 acc[2][6];
#pragma unroll
  for (int mi = 0; mi < 2; ++mi)
#pragma unroll
    for (int g = 0; g < 6; ++g) acc[mi][g] = 0.f;

  for (int kk = 0; kk < 16; ++kk) {
    __syncthreads();  // previous iteration's reads done
#pragma unroll
    for (int c = 0; c < 7; ++c) {
      int id = c * 256 + tid;  // 0..1791 chunks of 8 elements
      if (id < 128) {
        int r = id >> 2, kc = id & 3;
        *(uint4*)(Ay + r * BP + kc * 8) =
            *(const uint4*)(Yt + (size_t)(m0 + r) * 512 + kk * 32 + kc * 8);
      } else if (id < 256) {
        int id2 = id - 128;
        int r = id2 >> 2, kc = id2 & 3;
        const float* s = hprev + (size_t)(m0 + r) * 512 + kk * 32 + kc * 8;
        unsigned short o[8] __attribute__((aligned(16)));
#pragma unroll
        for (int j = 0; j < 8; ++j) o[j] = f2bf(s[j]);
        *(uint4*)(Ah + r * BP + kc * 8) = *(const uint4*)o;
      } else {
        int id2 = id - 256;  // 0..1535
        int g = id2 >> 8;    // 0..5
        int rem = id2 & 255;
        int r = rem >> 2, kc = rem & 3;
        const unsigned short* mat = (g < 3) ? Wiht : Whht;
        int gate = (g < 3) ? g : (g - 3);
        *(uint4*)(Bg + g * (64 * BP) + r * BP + kc * 8) =
            *(const uint4*)(mat + (size_t)(gate * 512 + j0 + r) * 512 + kk * 32 + kc * 8);
      }
    }
    __syncthreads();
    bf16x8 ay[2], ah[2];
#pragma unroll
    for (int mi = 0; mi < 2; ++mi) {
      ay[mi] = *(const bf16x8*)&Ay[(16 * mi + ml) * BP + qd * 8];
      ah[mi] = *(const bf16x8*)&Ah[(16 * mi + ml) * BP + qd * 8];
    }
#pragma unroll
    for (int g = 0; g < 6; ++g) {
      bf16x8 b = *(const bf16x8*)&Bg[g * (64 * BP) + (16 * wv + ml) * BP + qd * 8];
#pragma unroll
      for (int mi = 0; mi < 2; ++mi)
        acc[mi][g] = __builtin_amdgcn_mfma_f32_16x16x32_bf16((g < 3) ? ay[mi] : ah[mi], b,
                                                             acc[mi][g], 0, 0, 0);
    }
  }
  int j = j0 + 16 * wv + ml;
  float bi_r = bih[j], bi_z = bih[512 + j], bi_n = bih[1024 + j];
  float bh_r = bhh[j], bh_z = bhh[512 + j], bh_n = bhh[1024 + j];
#pragma unroll
  for (int mi = 0; mi < 2; ++mi)
#pragma unroll
    for (int r = 0; r < 4; ++r) {
      size_t row = (size_t)(m0 + 16 * mi + 4 * qd + r);
      float rg = acc[mi][0][r] + bi_r + acc[mi][3][r] + bh_r;
      rg = 1.f / (1.f + __expf(-rg));
      float zg = acc[mi][1][r] + bi_z + acc[mi][4][r] + bh_z;
      zg = 1.f / (1.f + __expf(-zg));
      float ng = tanhf(acc[mi][2][r] + bi_n + rg * (acc[mi][5][r] + bh_n));
      float hp = hprev[row * 512 + j];
      hnew[row * 512 + j] = (1.f - zg) * ng + zg * hp;
    }
}

__global__ void zero_h(float* hf) {
  int i = blockIdx.x * 256 + threadIdx.x;  // 2048 blocks -> 524288
  hf[i] = 0.f;
}

// ---------------------------------------------------------------------------
extern "C" void kernel_launch(void* const* d_in, const int* in_sizes, int n_in,
                              void* d_out, int out_size, void* d_ws, size_t ws_size,
                              hipStream_t stream) {
  (void)in_sizes; (void)n_in; (void)out_size; (void)ws_size;
  const float* xs    = (const float*)d_in[0];
  const float* obsW  = (const float*)d_in[1];
  const float* obsb  = (const float*)d_in[2];
  const float* obsg  = (const float*)d_in[3];
  const float* obsbe = (const float*)d_in[4];
  const float* W1    = (const float*)d_in[5];
  const float* b1    = (const float*)d_in[6];
  const float* g1    = (const float*)d_in[7];
  const float* be1   = (const float*)d_in[8];
  const float* W2    = (const float*)d_in[9];
  const float* b2    = (const float*)d_in[10];
  const float* g2    = (const float*)d_in[11];
  const float* be2   = (const float*)d_in[12];
  const float* Wo    = (const float*)d_in[13];
  const float* bo    = (const float*)d_in[14];
  const float* Wih   = (const float*)d_in[15];
  const float* bih   = (const float*)d_in[16];
  const float* Whh   = (const float*)d_in[17];
  const float* bhh   = (const float*)d_in[18];

  char* p = (char*)d_ws;
  auto take = [&](size_t bytes) { char* q = p; p += (bytes + 255) & ~(size_t)255; return q; };
  unsigned short* W1t  = (unsigned short*)take((size_t)512 * 512 * 2);
  unsigned short* W2t  = (unsigned short*)take((size_t)512 * 512 * 2);
  unsigned short* Wot  = (unsigned short*)take((size_t)512 * 512 * 2);
  unsigned short* Wiht = (unsigned short*)take((size_t)1536 * 512 * 2);
  unsigned short* Whht = (unsigned short*)take((size_t)1536 * 512 * 2);
  float* hf0 = (float*)take((size_t)1024 * 512 * 4);
  float* hf1 = (float*)take((size_t)1024 * 512 * 4);
  unsigned short* Yb = (unsigned short*)take((size_t)65536 * 512 * 2);  // largest last

  dim3 tb(32, 8);
  transpose_f2b<<<dim3(16, 16), tb, 0, stream>>>(W1, W1t, 512, 512);  // first 512 of 513 rows
  transpose_f2b<<<dim3(16, 16), tb, 0, stream>>>(W2, W2t, 512, 512);
  transpose_f2b<<<dim3(16, 16), tb, 0, stream>>>(Wo, Wot, 512, 512);
  transpose_f2b<<<dim3(48, 16), tb, 0, stream>>>(Wih, Wiht, 512, 1536);
  transpose_f2b<<<dim3(48, 16), tb, 0, stream>>>(Whh, Whht, 512, 1536);

  obs_embed<<<16384, 256, 0, stream>>>(xs, obsW, obsb, obsg, obsbe, Yb);

  // tr = W1 row 512 (the time row); folded into layer-1 bias per eval.
  ode_mega<<<2048, 512, 0, stream>>>(Yb, W1t, W2t, Wot, b1, W1 + 512 * 512, g1, be1, b2, g2,
                                     be2, bo, Yb);

  zero_h<<<2048, 256, 0, stream>>>(hf0);
  float* hf[2] = {hf0, hf1};
  for (int t = 0; t < 64; ++t) {
    int s = t & 1, d = s ^ 1;
    float* hn = (t == 63) ? (float*)d_out : hf[d];
    gru_step<<<dim3(32, 8), 256, 0, stream>>>(Yb + (size_t)t * 1024 * 512, hf[s], hn, Wiht, Whht,
                                              bih, bhh);
  }
}

// Round 4
// 8381.182 us; speedup vs baseline: 2.5633x; 2.5633x over previous
//
#include <hip/hip_runtime.h>
#include <stdint.h>

// ---------------------------------------------------------------------------
// ODE-RNN encoder, f32 I/O, bf16 MFMA internals.
// ODE phase: one batched row-local megakernel (64 rows/block, full 512-wide
// LN in-block). R4: pre-tiled weights -> conflict-free lane*16 LDS access,
// reg-staged double-buffered B window, launch_bounds(512,2) to kill spills.
// ---------------------------------------------------------------------------

typedef __bf16 bf16x8 __attribute__((ext_vector_type(8)));
typedef float floatx4 __attribute__((ext_vector_type(4)));

#define BP 40  // gru_step padded B row (ushorts)

static __device__ __forceinline__ float bf2f(unsigned short u) {
  union { unsigned int u32; float f; } c;
  c.u32 = ((unsigned int)u) << 16;
  return c.f;
}
static __device__ __forceinline__ unsigned short f2bf(float f) {
  union { __bf16 h; unsigned short u; } c;
  c.h = (__bf16)f;  // RNE
  return c.u;
}

// ---------------------------------------------------------------------------
// tile_weight: W (K=512 rows x N=512, f32 row-major) -> bf16 tiled
// [kk(16)][nt(32)][qd(4)][ml(16)][8] so that B-frag ds_read = base + lane*16.
// element (kk,nt,qd,ml,j) = W[kk*32+qd*8+j][nt*16+ml]
// ---------------------------------------------------------------------------
__global__ void tile_weight(const float* __restrict__ src, unsigned short* __restrict__ dst) {
  int t = blockIdx.x * 256 + threadIdx.x;  // 0..32767
  int ml = t & 15, qd = (t >> 4) & 3;
  int nt = (t >> 6) & 31, kk = t >> 11;
  int n = nt * 16 + ml;
  int k0 = kk * 32 + qd * 8;
  unsigned short o[8] __attribute__((aligned(16)));
#pragma unroll
  for (int j = 0; j < 8; ++j) o[j] = f2bf(src[(size_t)(k0 + j) * 512 + n]);
  *(uint4*)(dst + (size_t)t * 8) = *(const uint4*)o;
}

// ---------------------------------------------------------------------------
// transpose + f32->bf16 (GRU weights, [n][k] flat layout)
// ---------------------------------------------------------------------------
__global__ void transpose_f2b(const float* __restrict__ src, unsigned short* __restrict__ dst,
                              int R, int C) {
  __shared__ float t[32][33];
  int c0 = blockIdx.x * 32, r0 = blockIdx.y * 32;
  int tx = threadIdx.x, ty = threadIdx.y;  // 32 x 8
#pragma unroll
  for (int i = 0; i < 32; i += 8) t[ty + i][tx] = src[(size_t)(r0 + ty + i) * C + c0 + tx];
  __syncthreads();
#pragma unroll
  for (int i = 0; i < 32; i += 8) dst[(size_t)(c0 + ty + i) * R + r0 + tx] = f2bf(t[tx][ty + i]);
}

// ---------------------------------------------------------------------------
// obs embed: y = leaky(LN(xs @ W + b)) (f32 in, bf16 out), one wave per row
// ---------------------------------------------------------------------------
__global__ __launch_bounds__(256) void obs_embed(
    const float* __restrict__ xs, const float* __restrict__ W,
    const float* __restrict__ bias, const float* __restrict__ gam,
    const float* __restrict__ bet, unsigned short* __restrict__ Y) {
  __shared__ float Wl[4096];
  const int tid = threadIdx.x, lane = tid & 63, wv = tid >> 6;
#pragma unroll
  for (int i = 0; i < 16; ++i) Wl[i * 256 + tid] = W[i * 256 + tid];
  __syncthreads();
  size_t row = (size_t)blockIdx.x * 4 + wv;
  float xf[8];
  {
    const float* xp = xs + row * 8;
#pragma unroll
    for (int k = 0; k < 8; ++k) xf[k] = xp[k];
  }
  int n0 = lane * 8;
  float a[8];
#pragma unroll
  for (int j = 0; j < 8; ++j) a[j] = bias[n0 + j];
#pragma unroll
  for (int k = 0; k < 8; ++k)
#pragma unroll
    for (int j = 0; j < 8; ++j) a[j] += xf[k] * Wl[k * 512 + n0 + j];
  float s1 = 0.f, s2 = 0.f;
#pragma unroll
  for (int j = 0; j < 8; ++j) { s1 += a[j]; s2 += a[j] * a[j]; }
#pragma unroll
  for (int off = 1; off < 64; off <<= 1) { s1 += __shfl_xor(s1, off); s2 += __shfl_xor(s2, off); }
  float mean = s1 * (1.f / 512.f);
  float rstd = rsqrtf(s2 * (1.f / 512.f) - mean * mean + 1e-5f);
  unsigned short o[8] __attribute__((aligned(16)));
#pragma unroll
  for (int j = 0; j < 8; ++j) {
    float v = (a[j] - mean) * rstd * gam[n0 + j] + bet[n0 + j];
    v = v > 0.f ? v : 0.01f * v;
    o[j] = f2bf(v);
  }
  *(uint4*)(Y + row * 512 + n0) = *(const uint4*)o;
}

// ---------------------------------------------------------------------------
// ODE megakernel. A (64x512) in tiled LDS layout [mt][kk][qd][ml][8]; B
// streamed through a double-buffered 32KB window in the same tiled layout.
// All MFMA fragment LDS reads are base + lane*16 (conflict-free).
// ---------------------------------------------------------------------------

// element (row, n) address in tiled A (ushort index)
static __device__ __forceinline__ int a_addr(int row, int n) {
  return (((row >> 4) * 16 + (n >> 5)) * 4 + ((n >> 3) & 3)) * 128 + (row & 15) * 8 + (n & 7);
}

static __device__ __forceinline__ void gemm64(const unsigned short* __restrict__ Wt,
                                              const unsigned short* As, unsigned short* Bs,
                                              int tid, int wv, int lane, floatx4 (&acc)[4][4]) {
#pragma unroll
  for (int mt = 0; mt < 4; ++mt)
#pragma unroll
    for (int ni = 0; ni < 4; ++ni) acc[mt][ni] = 0.f;
  const char* gb = (const char*)Wt;
  uint4 st[4];
#pragma unroll
  for (int i = 0; i < 4; ++i) st[i] = *(const uint4*)(gb + i * 8192 + tid * 16);
#pragma unroll
  for (int i = 0; i < 4; ++i) *(uint4*)((char*)Bs + i * 8192 + tid * 16) = st[i];
  __syncthreads();
  for (int kk = 0; kk < 16; ++kk) {
    const unsigned short* cur = Bs + (kk & 1) * 16384;
    unsigned short* nxt = Bs + ((kk + 1) & 1) * 16384;
    if (kk < 15) {
#pragma unroll
      for (int i = 0; i < 4; ++i)
        st[i] = *(const uint4*)(gb + (size_t)(kk + 1) * 32768 + i * 8192 + tid * 16);
    }
    bf16x8 a[4], b[4];
#pragma unroll
    for (int mt = 0; mt < 4; ++mt) a[mt] = *(const bf16x8*)&As[(mt * 16 + kk) * 512 + lane * 8];
#pragma unroll
    for (int ni = 0; ni < 4; ++ni) b[ni] = *(const bf16x8*)&cur[(4 * wv + ni) * 512 + lane * 8];
#pragma unroll
    for (int mt = 0; mt < 4; ++mt)
#pragma unroll
      for (int ni = 0; ni < 4; ++ni)
        acc[mt][ni] = __builtin_amdgcn_mfma_f32_16x16x32_bf16(a[mt], b[ni], acc[mt][ni], 0, 0, 0);
    if (kk < 15) {
#pragma unroll
      for (int i = 0; i < 4; ++i) *(uint4*)((char*)nxt + i * 8192 + tid * 16) = st[i];
    }
    __syncthreads();
  }
}

// LN + leaky epilogue; bias (+ optional t*trow) from bf16 LDS params; writes
// bf16 result into tiled As.
static __device__ __forceinline__ void ln_epi64(floatx4 (&acc)[4][4], unsigned short* As,
                                                const unsigned short* Ps, int pb, int pg, int pbe,
                                                bool addt, float tval, int wv, int lane, int tid,
                                                float2* red, float* stat) {
  const int ml = lane & 15, qd = lane >> 4;
#pragma unroll
  for (int ni = 0; ni < 4; ++ni) {
    int n = (4 * wv + ni) * 16 + ml;
    float bias = bf2f(Ps[pb * 512 + n]);
    if (addt) bias += tval * bf2f(Ps[512 + n]);
#pragma unroll
    for (int mt = 0; mt < 4; ++mt)
#pragma unroll
      for (int r = 0; r < 4; ++r) acc[mt][ni][r] += bias;
  }
#pragma unroll
  for (int mt = 0; mt < 4; ++mt)
#pragma unroll
    for (int r = 0; r < 4; ++r) {
      float s1 = 0.f, s2 = 0.f;
#pragma unroll
      for (int ni = 0; ni < 4; ++ni) { float x = acc[mt][ni][r]; s1 += x; s2 += x * x; }
#pragma unroll
      for (int off = 1; off < 16; off <<= 1) { s1 += __shfl_xor(s1, off); s2 += __shfl_xor(s2, off); }
      if (ml == 0) red[(mt * 16 + 4 * qd + r) * 8 + wv] = make_float2(s1, s2);
    }
  __syncthreads();
  if (tid < 64) {
    float S1 = 0.f, S2 = 0.f;
#pragma unroll
    for (int w = 0; w < 8; ++w) { float2 v = red[tid * 8 + w]; S1 += v.x; S2 += v.y; }
    float mean = S1 * (1.f / 512.f);
    float var = S2 * (1.f / 512.f) - mean * mean;
    stat[tid * 2] = mean;
    stat[tid * 2 + 1] = rsqrtf(var + 1e-5f);
  }
  __syncthreads();
#pragma unroll
  for (int mt = 0; mt < 4; ++mt)
#pragma unroll
    for (int r = 0; r < 4; ++r) {
      int row = mt * 16 + 4 * qd + r;
      float mean = stat[row * 2], rstd = stat[row * 2 + 1];
#pragma unroll
      for (int ni = 0; ni < 4; ++ni) {
        int n = (4 * wv + ni) * 16 + ml;
        float x = (acc[mt][ni][r] - mean) * rstd * bf2f(Ps[pg * 512 + n]) + bf2f(Ps[pbe * 512 + n]);
        x = x > 0.f ? x : 0.01f * x;
        As[a_addr(row, n)] = f2bf(x);
      }
    }
  __syncthreads();
}

// RK4 stage: k = acc + bout; h fp32 regs, ksum packed bf16 pairs; writes next
// stage input y (bf16) into tiled As.
static __device__ __forceinline__ void stage_epi64(floatx4 (&acc)[4][4], float (&h)[4][4][4],
                                                   unsigned int (&ks)[4][4][2], unsigned short* As,
                                                   const unsigned short* Ps, int stg, int wv,
                                                   int lane) {
  const int ml = lane & 15, qd = lane >> 4;
#pragma unroll
  for (int mt = 0; mt < 4; ++mt)
#pragma unroll
    for (int ni = 0; ni < 4; ++ni) {
      int n = (4 * wv + ni) * 16 + ml;
      float bias = bf2f(Ps[7 * 512 + n]);
#pragma unroll
      for (int rp = 0; rp < 2; ++rp) {
        float kv0 = acc[mt][ni][2 * rp] + bias;
        float kv1 = acc[mt][ni][2 * rp + 1] + bias;
        unsigned int pk = ks[mt][ni][rp];
        float s0 = bf2f((unsigned short)(pk & 0xffffu));
        float s1 = bf2f((unsigned short)(pk >> 16));
        float h0 = h[mt][ni][2 * rp], h1 = h[mt][ni][2 * rp + 1];
        float y0, y1;
        if (stg == 0)      { s0 = kv0;        s1 = kv1;        y0 = h0 + 0.125f * kv0; y1 = h1 + 0.125f * kv1; }
        else if (stg == 1) { s0 += 2.f * kv0; s1 += 2.f * kv1; y0 = h0 + 0.125f * kv0; y1 = h1 + 0.125f * kv1; }
        else if (stg == 2) { s0 += 2.f * kv0; s1 += 2.f * kv1; y0 = h0 + 0.25f * kv0;  y1 = h1 + 0.25f * kv1; }
        else {
          h0 += (1.f / 24.f) * (s0 + kv0);  // dt/6, dt=0.25
          h1 += (1.f / 24.f) * (s1 + kv1);
          h[mt][ni][2 * rp] = h0; h[mt][ni][2 * rp + 1] = h1;
          y0 = h0; y1 = h1;
        }
        ks[mt][ni][rp] = (unsigned int)f2bf(s0) | ((unsigned int)f2bf(s1) << 16);
        int row = mt * 16 + 4 * qd + 2 * rp;
        As[a_addr(row, n)] = f2bf(y0);
        As[a_addr(row + 1, n)] = f2bf(y1);
      }
    }
  __syncthreads();
}

__global__ __launch_bounds__(512, 2) void ode_mega(
    const unsigned short* Y, const unsigned short* __restrict__ W1t,
    const unsigned short* __restrict__ W2t, const unsigned short* __restrict__ Wot,
    const float* __restrict__ b1, const float* __restrict__ tr, const float* __restrict__ g1,
    const float* __restrict__ be1, const float* __restrict__ b2, const float* __restrict__ g2,
    const float* __restrict__ be2, const float* __restrict__ bo, unsigned short* Yout) {
  __shared__ __align__(16) unsigned short As[32768];  // 64KB tiled A
  __shared__ __align__(16) unsigned short Bs[32768];  // 2 x 32KB B window
  __shared__ __align__(16) unsigned short Ps[4096];   // 8 x 512 bf16 params
  __shared__ float2 red[512];                         // 4KB
  __shared__ float stat[128];                         // 512B

  const int tid = threadIdx.x;
  const int lane = tid & 63;
  const int wv = tid >> 6;
  const int ml = lane & 15;
  const int qd = lane >> 4;
  const size_t m0 = (size_t)blockIdx.x * 64;

  {
    const float* srcs[8] = {b1, tr, g1, be1, b2, g2, be2, bo};
#pragma unroll
    for (int v = 0; v < 8; ++v) Ps[v * 512 + tid] = f2bf(srcs[v][tid]);
  }
  // stage initial A: thread owns row r = tid>>3, chunks c = i*8 + (tid&7)
  {
    int r = tid >> 3;
#pragma unroll
    for (int i = 0; i < 8; ++i) {
      int c = i * 8 + (tid & 7);
      uint4 v = *(const uint4*)(Y + (m0 + r) * 512 + c * 8);
      int dst = (((r >> 4) * 16 + (c >> 2)) * 4 + (c & 3)) * 128 + (r & 15) * 8;
      *(uint4*)(As + dst) = v;
    }
  }
  __syncthreads();

  float h[4][4][4];          // fp32 ODE state, MFMA C-layout
  unsigned int ks[4][4][2];  // RK4 ksum, packed bf16 pairs
#pragma unroll
  for (int mt = 0; mt < 4; ++mt)
#pragma unroll
    for (int ni = 0; ni < 4; ++ni) {
      ks[mt][ni][0] = 0u; ks[mt][ni][1] = 0u;
      int n = (4 * wv + ni) * 16 + ml;
#pragma unroll
      for (int r = 0; r < 4; ++r) h[mt][ni][r] = bf2f(As[a_addr(mt * 16 + 4 * qd + r, n)]);
    }

  for (int e = 0; e < 16; ++e) {  // 4 RK4 steps x 4 stages
    int stg = e & 3;
    float tval = 0.25f * (float)(e >> 2) + ((stg == 3) ? 0.25f : (stg ? 0.125f : 0.f));
    floatx4 acc[4][4];
    gemm64(W1t, As, Bs, tid, wv, lane, acc);
    ln_epi64(acc, As, Ps, 0, 2, 3, true, tval, wv, lane, tid, red, stat);
    gemm64(W2t, As, Bs, tid, wv, lane, acc);
    ln_epi64(acc, As, Ps, 4, 5, 6, false, 0.f, wv, lane, tid, red, stat);
    gemm64(Wot, As, Bs, tid, wv, lane, acc);
    stage_epi64(acc, h, ks, As, Ps, stg, wv, lane);
  }

  // final h_ode (bf16, row-major) for the GRU phase
#pragma unroll
  for (int mt = 0; mt < 4; ++mt)
#pragma unroll
    for (int ni = 0; ni < 4; ++ni)
#pragma unroll
      for (int r = 0; r < 4; ++r) {
        size_t row = m0 + mt * 16 + 4 * qd + r;
        int n = (4 * wv + ni) * 16 + ml;
        Yout[row * 512 + n] = f2bf(h[mt][ni][r]);
      }
}

// ---------------------------------------------------------------------------
// GRU step (unchanged from R3): gi = y_t @ W_ih, gh = h_prev @ W_hh, gates.
// grid (32, 8): 32 rows x 64 gate-cols per block, 4 waves.
// ---------------------------------------------------------------------------
__global__ __launch_bounds__(256) void gru_step(
    const unsigned short* __restrict__ Yt, const float* __restrict__ hprev,
    float* __restrict__ hnew, const unsigned short* __restrict__ Wiht,
    const unsigned short* __restrict__ Whht, const float* __restrict__ bih,
    const float* __restrict__ bhh) {
  __shared__ __align__(16) unsigned short Ay[32 * BP];
  __shared__ __align__(16) unsigned short Ah[32 * BP];
  __shared__ __align__(16) unsigned short Bg[6 * 64 * BP];
  const int tid = threadIdx.x, lane = tid & 63, wv = tid >> 6;
  const int ml = lane & 15, qd = lane >> 4;
  const int m0 = blockIdx.x * 32;
  const int j0 = blockIdx.y * 64;

  floatx4 acc[2][6];
#pragma unroll
  for (int mi = 0; mi < 2; ++mi)
#pragma unroll
    for (int g = 0; g < 6; ++g) acc[mi][g] = 0.f;

  for (int kk = 0; kk < 16; ++kk) {
    __syncthreads();
#pragma unroll
    for (int c = 0; c < 7; ++c) {
      int id = c * 256 + tid;
      if (id < 128) {
        int r = id >> 2, kc = id & 3;
        *(uint4*)(Ay + r * BP + kc * 8) =
            *(const uint4*)(Yt + (size_t)(m0 + r) * 512 + kk * 32 + kc * 8);
      } else if (id < 256) {
        int id2 = id - 128;
        int r = id2 >> 2, kc = id2 & 3;
        const float* s = hprev + (size_t)(m0 + r) * 512 + kk * 32 + kc * 8;
        unsigned short o[8] __attribute__((aligned(16)));
#pragma unroll
        for (int j = 0; j < 8; ++j) o[j] = f2bf(s[j]);
        *(uint4*)(Ah + r * BP + kc * 8) = *(const uint4*)o;
      } else {
        int id2 = id - 256;
        int g = id2 >> 8;
        int rem = id2 & 255;
        int r = rem >> 2, kc = rem & 3;
        const unsigned short* mat = (g < 3) ? Wiht : Whht;
        int gate = (g < 3) ? g : (g - 3);
        *(uint4*)(Bg + g * (64 * BP) + r * BP + kc * 8) =
            *(const uint4*)(mat + (size_t)(gate * 512 + j0 + r) * 512 + kk * 32 + kc * 8);
      }
    }
    __syncthreads();
    bf16x8 ay[2], ah[2];
#pragma unroll
    for (int mi = 0; mi < 2; ++mi) {
      ay[mi] = *(const bf16x8*)&Ay[(16 * mi + ml) * BP + qd * 8];
      ah[mi] = *(const bf16x8*)&Ah[(16 * mi + ml) * BP + qd * 8];
    }
#pragma unroll
    for (int g = 0; g < 6; ++g) {
      bf16x8 b = *(const bf16x8*)&Bg[g * (64 * BP) + (16 * wv + ml) * BP + qd * 8];
#pragma unroll
      for (int mi = 0; mi < 2; ++mi)
        acc[mi][g] = __builtin_amdgcn_mfma_f32_16x16x32_bf16((g < 3) ? ay[mi] : ah[mi], b,
                                                             acc[mi][g], 0, 0, 0);
    }
  }
  int j = j0 + 16 * wv + ml;
  float bi_r = bih[j], bi_z = bih[512 + j], bi_n = bih[1024 + j];
  float bh_r = bhh[j], bh_z = bhh[512 + j], bh_n = bhh[1024 + j];
#pragma unroll
  for (int mi = 0; mi < 2; ++mi)
#pragma unroll
    for (int r = 0; r < 4; ++r) {
      size_t row = (size_t)(m0 + 16 * mi + 4 * qd + r);
      float rg = acc[mi][0][r] + bi_r + acc[mi][3][r] + bh_r;
      rg = 1.f / (1.f + __expf(-rg));
      float zg = acc[mi][1][r] + bi_z + acc[mi][4][r] + bh_z;
      zg = 1.f / (1.f + __expf(-zg));
      float ng = tanhf(acc[mi][2][r] + bi_n + rg * (acc[mi][5][r] + bh_n));
      float hp = hprev[row * 512 + j];
      hnew[row * 512 + j] = (1.f - zg) * ng + zg * hp;
    }
}

__global__ void zero_h(float* hf) {
  int i = blockIdx.x * 256 + threadIdx.x;
  hf[i] = 0.f;
}

// ---------------------------------------------------------------------------
extern "C" void kernel_launch(void* const* d_in, const int* in_sizes, int n_in,
                              void* d_out, int out_size, void* d_ws, size_t ws_size,
                              hipStream_t stream) {
  (void)in_sizes; (void)n_in; (void)out_size; (void)ws_size;
  const float* xs    = (const float*)d_in[0];
  const float* obsW  = (const float*)d_in[1];
  const float* obsb  = (const float*)d_in[2];
  const float* obsg  = (const float*)d_in[3];
  const float* obsbe = (const float*)d_in[4];
  const float* W1    = (const float*)d_in[5];
  const float* b1    = (const float*)d_in[6];
  const float* g1    = (const float*)d_in[7];
  const float* be1   = (const float*)d_in[8];
  const float* W2    = (const float*)d_in[9];
  const float* b2    = (const float*)d_in[10];
  const float* g2    = (const float*)d_in[11];
  const float* be2   = (const float*)d_in[12];
  const float* Wo    = (const float*)d_in[13];
  const float* bo    = (const float*)d_in[14];
  const float* Wih   = (const float*)d_in[15];
  const float* bih   = (const float*)d_in[16];
  const float* Whh   = (const float*)d_in[17];
  const float* bhh   = (const float*)d_in[18];

  char* p = (char*)d_ws;
  auto take = [&](size_t bytes) { char* q = p; p += (bytes + 255) & ~(size_t)255; return q; };
  unsigned short* W1t  = (unsigned short*)take((size_t)512 * 512 * 2);
  unsigned short* W2t  = (unsigned short*)take((size_t)512 * 512 * 2);
  unsigned short* Wot  = (unsigned short*)take((size_t)512 * 512 * 2);
  unsigned short* Wiht = (unsigned short*)take((size_t)1536 * 512 * 2);
  unsigned short* Whht = (unsigned short*)take((size_t)1536 * 512 * 2);
  float* hf0 = (float*)take((size_t)1024 * 512 * 4);
  float* hf1 = (float*)take((size_t)1024 * 512 * 4);
  unsigned short* Yb = (unsigned short*)take((size_t)65536 * 512 * 2);

  dim3 tb(32, 8);
  tile_weight<<<128, 256, 0, stream>>>(W1, W1t);  // first 512 of 513 rows
  tile_weight<<<128, 256, 0, stream>>>(W2, W2t);
  tile_weight<<<128, 256, 0, stream>>>(Wo, Wot);
  transpose_f2b<<<dim3(48, 16), tb, 0, stream>>>(Wih, Wiht, 512, 1536);
  transpose_f2b<<<dim3(48, 16), tb, 0, stream>>>(Whh, Whht, 512, 1536);

  obs_embed<<<16384, 256, 0, stream>>>(xs, obsW, obsb, obsg, obsbe, Yb);

  // tr = W1 row 512 (time row), folded into layer-1 bias per eval.
  ode_mega<<<1024, 512, 0, stream>>>(Yb, W1t, W2t, Wot, b1, W1 + 512 * 512, g1, be1, b2, g2,
                                     be2, bo, Yb);

  zero_h<<<2048, 256, 0, stream>>>(hf0);
  float* hf[2] = {hf0, hf1};
  for (int t = 0; t < 64; ++t) {
    int s = t & 1, d = s ^ 1;
    float* hn = (t == 63) ? (float*)d_out : hf[d];
    gru_step<<<dim3(32, 8), 256, 0, stream>>>(Yb + (size_t)t * 1024 * 512, hf[s], hn, Wiht, Whht,
                                              bih, bhh);
  }
}

// Round 5
// 7830.117 us; speedup vs baseline: 2.7437x; 1.0704x over previous
//
#include <hip/hip_runtime.h>
#include <stdint.h>

// ---------------------------------------------------------------------------
// ODE-RNN encoder, f32 I/O, bf16 MFMA internals.
// R5: barrier-free K-loop. B operand is per-wave-private -> load straight
// global->VGPR (coalesced dwordx4 via tiled weights), 2-slab double buffer,
// cross-GEMM prefetch. Epilogue barriers are lgkm-only raw barriers so weight
// loads stay in flight. amdgpu_waves_per_eu(2,2) unlocks 256-VGPR budget
// (LDS caps at 1 block/CU anyway) to kill the residual spills.
// ---------------------------------------------------------------------------

typedef __bf16 bf16x8 __attribute__((ext_vector_type(8)));
typedef float floatx4 __attribute__((ext_vector_type(4)));

#define BP 40  // gru_step padded B row (ushorts)

static __device__ __forceinline__ float bf2f(unsigned short u) {
  union { unsigned int u32; float f; } c;
  c.u32 = ((unsigned int)u) << 16;
  return c.f;
}
static __device__ __forceinline__ unsigned short f2bf(float f) {
  union { __bf16 h; unsigned short u; } c;
  c.h = (__bf16)f;  // RNE
  return c.u;
}

// LDS-only barrier: does NOT drain vmcnt, so global prefetches stay in flight.
static __device__ __forceinline__ void barrier_lds() {
  __asm__ volatile("s_waitcnt lgkmcnt(0)\n\ts_barrier" ::: "memory");
}

// ---------------------------------------------------------------------------
// tile_weight: W (K=512 x N=512, f32 row-major) -> bf16 tiled
// [kk(16)][nt(32)][qd(4)][ml(16)][8]; element (kk,nt,qd,ml,j) = W[kk*32+qd*8+j][nt*16+ml]
// ---------------------------------------------------------------------------
__global__ void tile_weight(const float* __restrict__ src, unsigned short* __restrict__ dst) {
  int t = blockIdx.x * 256 + threadIdx.x;  // 0..32767
  int ml = t & 15, qd = (t >> 4) & 3;
  int nt = (t >> 6) & 31, kk = t >> 11;
  int n = nt * 16 + ml;
  int k0 = kk * 32 + qd * 8;
  unsigned short o[8] __attribute__((aligned(16)));
#pragma unroll
  for (int j = 0; j < 8; ++j) o[j] = f2bf(src[(size_t)(k0 + j) * 512 + n]);
  *(uint4*)(dst + (size_t)t * 8) = *(const uint4*)o;
}

// ---------------------------------------------------------------------------
// transpose + f32->bf16 (GRU weights, [n][k] flat layout)
// ---------------------------------------------------------------------------
__global__ void transpose_f2b(const float* __restrict__ src, unsigned short* __restrict__ dst,
                              int R, int C) {
  __shared__ float t[32][33];
  int c0 = blockIdx.x * 32, r0 = blockIdx.y * 32;
  int tx = threadIdx.x, ty = threadIdx.y;  // 32 x 8
#pragma unroll
  for (int i = 0; i < 32; i += 8) t[ty + i][tx] = src[(size_t)(r0 + ty + i) * C + c0 + tx];
  __syncthreads();
#pragma unroll
  for (int i = 0; i < 32; i += 8) dst[(size_t)(c0 + ty + i) * R + r0 + tx] = f2bf(t[tx][ty + i]);
}

// ---------------------------------------------------------------------------
// obs embed: y = leaky(LN(xs @ W + b)) (f32 in, bf16 out), one wave per row
// ---------------------------------------------------------------------------
__global__ __launch_bounds__(256) void obs_embed(
    const float* __restrict__ xs, const float* __restrict__ W,
    const float* __restrict__ bias, const float* __restrict__ gam,
    const float* __restrict__ bet, unsigned short* __restrict__ Y) {
  __shared__ float Wl[4096];
  const int tid = threadIdx.x, lane = tid & 63, wv = tid >> 6;
#pragma unroll
  for (int i = 0; i < 16; ++i) Wl[i * 256 + tid] = W[i * 256 + tid];
  __syncthreads();
  size_t row = (size_t)blockIdx.x * 4 + wv;
  float xf[8];
  {
    const float* xp = xs + row * 8;
#pragma unroll
    for (int k = 0; k < 8; ++k) xf[k] = xp[k];
  }
  int n0 = lane * 8;
  float a[8];
#pragma unroll
  for (int j = 0; j < 8; ++j) a[j] = bias[n0 + j];
#pragma unroll
  for (int k = 0; k < 8; ++k)
#pragma unroll
    for (int j = 0; j < 8; ++j) a[j] += xf[k] * Wl[k * 512 + n0 + j];
  float s1 = 0.f, s2 = 0.f;
#pragma unroll
  for (int j = 0; j < 8; ++j) { s1 += a[j]; s2 += a[j] * a[j]; }
#pragma unroll
  for (int off = 1; off < 64; off <<= 1) { s1 += __shfl_xor(s1, off); s2 += __shfl_xor(s2, off); }
  float mean = s1 * (1.f / 512.f);
  float rstd = rsqrtf(s2 * (1.f / 512.f) - mean * mean + 1e-5f);
  unsigned short o[8] __attribute__((aligned(16)));
#pragma unroll
  for (int j = 0; j < 8; ++j) {
    float v = (a[j] - mean) * rstd * gam[n0 + j] + bet[n0 + j];
    v = v > 0.f ? v : 0.01f * v;
    o[j] = f2bf(v);
  }
  *(uint4*)(Y + row * 512 + n0) = *(const uint4*)o;
}

// ---------------------------------------------------------------------------
// ODE megakernel. A (64x512) resident in tiled LDS [mt][kk][qd][ml][8];
// B fragments stream global->VGPR (per-wave-private), no K-loop barriers.
// ---------------------------------------------------------------------------

// element (row, n) address in tiled A (ushort index)
static __device__ __forceinline__ int a_addr(int row, int n) {
  return (((row >> 4) * 16 + (n >> 5)) * 4 + ((n >> 3) & 3)) * 128 + (row & 15) * 8 + (n & 7);
}

static __device__ __forceinline__ void bload(const unsigned short* __restrict__ Wt, int kk,
                                             int wv, int lane, bf16x8 (&b)[4]) {
#pragma unroll
  for (int ni = 0; ni < 4; ++ni)
    b[ni] = *(const bf16x8*)(Wt + ((size_t)kk * 32 + 4 * wv + ni) * 512 + (size_t)lane * 8);
}

// bb must hold Wt slabs {0,1} on entry; holds Wnext slabs {0,1} on exit.
static __device__ __forceinline__ void gemm64d(const unsigned short* __restrict__ Wt,
                                               const unsigned short* __restrict__ Wnext,
                                               const unsigned short* As, int wv, int lane,
                                               bf16x8 (&bb)[2][4], floatx4 (&acc)[4][4]) {
#pragma unroll
  for (int mt = 0; mt < 4; ++mt)
#pragma unroll
    for (int ni = 0; ni < 4; ++ni) acc[mt][ni] = 0.f;
#pragma unroll
  for (int kk = 0; kk < 16; ++kk) {
    bf16x8 a[4];
#pragma unroll
    for (int mt = 0; mt < 4; ++mt) a[mt] = *(const bf16x8*)&As[(mt * 16 + kk) * 512 + lane * 8];
#pragma unroll
    for (int mt = 0; mt < 4; ++mt)
#pragma unroll
      for (int ni = 0; ni < 4; ++ni)
        acc[mt][ni] =
            __builtin_amdgcn_mfma_f32_16x16x32_bf16(a[mt], bb[kk & 1][ni], acc[mt][ni], 0, 0, 0);
    // refill the just-consumed slot: kk+2 of this weight, or next weight's 0/1
    if (kk < 14) bload(Wt, kk + 2, wv, lane, bb[kk & 1]);
    else bload(Wnext, kk - 14, wv, lane, bb[kk & 1]);
  }
}

// LN + leaky epilogue; writes bf16 result into tiled As.
static __device__ __forceinline__ void ln_epi64(floatx4 (&acc)[4][4], unsigned short* As,
                                                const unsigned short* Ps, int pb, int pg, int pbe,
                                                bool addt, float tval, int wv, int lane, int tid,
                                                float2* red, float* stat) {
  const int ml = lane & 15, qd = lane >> 4;
#pragma unroll
  for (int ni = 0; ni < 4; ++ni) {
    int n = (4 * wv + ni) * 16 + ml;
    float bias = bf2f(Ps[pb * 512 + n]);
    if (addt) bias += tval * bf2f(Ps[512 + n]);
#pragma unroll
    for (int mt = 0; mt < 4; ++mt)
#pragma unroll
      for (int r = 0; r < 4; ++r) acc[mt][ni][r] += bias;
  }
#pragma unroll
  for (int mt = 0; mt < 4; ++mt)
#pragma unroll
    for (int r = 0; r < 4; ++r) {
      float s1 = 0.f, s2 = 0.f;
#pragma unroll
      for (int ni = 0; ni < 4; ++ni) { float x = acc[mt][ni][r]; s1 += x; s2 += x * x; }
#pragma unroll
      for (int off = 1; off < 16; off <<= 1) { s1 += __shfl_xor(s1, off); s2 += __shfl_xor(s2, off); }
      if (ml == 0) red[(mt * 16 + 4 * qd + r) * 8 + wv] = make_float2(s1, s2);
    }
  barrier_lds();  // red visible; also: all waves past their As a-frag reads
  if (tid < 64) {
    float S1 = 0.f, S2 = 0.f;
#pragma unroll
    for (int w = 0; w < 8; ++w) { float2 v = red[tid * 8 + w]; S1 += v.x; S2 += v.y; }
    float mean = S1 * (1.f / 512.f);
    float var = S2 * (1.f / 512.f) - mean * mean;
    stat[tid * 2] = mean;
    stat[tid * 2 + 1] = rsqrtf(var + 1e-5f);
  }
  barrier_lds();
#pragma unroll
  for (int mt = 0; mt < 4; ++mt)
#pragma unroll
    for (int r = 0; r < 4; ++r) {
      int row = mt * 16 + 4 * qd + r;
      float mean = stat[row * 2], rstd = stat[row * 2 + 1];
#pragma unroll
      for (int ni = 0; ni < 4; ++ni) {
        int n = (4 * wv + ni) * 16 + ml;
        float x = (acc[mt][ni][r] - mean) * rstd * bf2f(Ps[pg * 512 + n]) + bf2f(Ps[pbe * 512 + n]);
        x = x > 0.f ? x : 0.01f * x;
        As[a_addr(row, n)] = f2bf(x);
      }
    }
  barrier_lds();  // As writes visible
}

// RK4 stage: k = acc + bout; h fp32, ksum packed bf16 pairs; writes y into As.
static __device__ __forceinline__ void stage_epi64(floatx4 (&acc)[4][4], float (&h)[4][4][4],
                                                   unsigned int (&ks)[4][4][2], unsigned short* As,
                                                   const unsigned short* Ps, int stg, int wv,
                                                   int lane) {
  const int ml = lane & 15, qd = lane >> 4;
  barrier_lds();  // K-loop has no barriers: ensure all waves done reading As
#pragma unroll
  for (int mt = 0; mt < 4; ++mt)
#pragma unroll
    for (int ni = 0; ni < 4; ++ni) {
      int n = (4 * wv + ni) * 16 + ml;
      float bias = bf2f(Ps[7 * 512 + n]);
#pragma unroll
      for (int rp = 0; rp < 2; ++rp) {
        float kv0 = acc[mt][ni][2 * rp] + bias;
        float kv1 = acc[mt][ni][2 * rp + 1] + bias;
        unsigned int pk = ks[mt][ni][rp];
        float s0 = bf2f((unsigned short)(pk & 0xffffu));
        float s1 = bf2f((unsigned short)(pk >> 16));
        float h0 = h[mt][ni][2 * rp], h1 = h[mt][ni][2 * rp + 1];
        float y0, y1;
        if (stg == 0)      { s0 = kv0;        s1 = kv1;        y0 = h0 + 0.125f * kv0; y1 = h1 + 0.125f * kv1; }
        else if (stg == 1) { s0 += 2.f * kv0; s1 += 2.f * kv1; y0 = h0 + 0.125f * kv0; y1 = h1 + 0.125f * kv1; }
        else if (stg == 2) { s0 += 2.f * kv0; s1 += 2.f * kv1; y0 = h0 + 0.25f * kv0;  y1 = h1 + 0.25f * kv1; }
        else {
          h0 += (1.f / 24.f) * (s0 + kv0);  // dt/6, dt=0.25
          h1 += (1.f / 24.f) * (s1 + kv1);
          h[mt][ni][2 * rp] = h0; h[mt][ni][2 * rp + 1] = h1;
          y0 = h0; y1 = h1;
        }
        ks[mt][ni][rp] = (unsigned int)f2bf(s0) | ((unsigned int)f2bf(s1) << 16);
        int row = mt * 16 + 4 * qd + 2 * rp;
        As[a_addr(row, n)] = f2bf(y0);
        As[a_addr(row + 1, n)] = f2bf(y1);
      }
    }
  barrier_lds();  // As writes visible
}

__global__ __launch_bounds__(512) __attribute__((amdgpu_waves_per_eu(2, 2))) void ode_mega(
    const unsigned short* Y, const unsigned short* __restrict__ W1t,
    const unsigned short* __restrict__ W2t, const unsigned short* __restrict__ Wot,
    const float* __restrict__ b1, const float* __restrict__ tr, const float* __restrict__ g1,
    const float* __restrict__ be1, const float* __restrict__ b2, const float* __restrict__ g2,
    const float* __restrict__ be2, const float* __restrict__ bo, unsigned short* Yout) {
  __shared__ __align__(16) unsigned short As[32768];  // 64KB tiled A
  __shared__ __align__(16) unsigned short Ps[4096];   // 8 x 512 bf16 params
  __shared__ float2 red[512];                         // 4KB
  __shared__ float stat[128];                         // 512B  -> ~77KB total

  const int tid = threadIdx.x;
  const int lane = tid & 63;
  const int wv = tid >> 6;
  const int ml = lane & 15;
  const int qd = lane >> 4;
  const size_t m0 = (size_t)blockIdx.x * 64;

  // start weight prefetch immediately
  bf16x8 bb[2][4];
  bload(W1t, 0, wv, lane, bb[0]);
  bload(W1t, 1, wv, lane, bb[1]);

  {
    const float* srcs[8] = {b1, tr, g1, be1, b2, g2, be2, bo};
#pragma unroll
    for (int v = 0; v < 8; ++v) Ps[v * 512 + tid] = f2bf(srcs[v][tid]);
  }
  // stage initial A: thread owns row r = tid>>3, chunks c = i*8 + (tid&7)
  {
    int r = tid >> 3;
#pragma unroll
    for (int i = 0; i < 8; ++i) {
      int c = i * 8 + (tid & 7);
      uint4 v = *(const uint4*)(Y + (m0 + r) * 512 + c * 8);
      int dst = (((r >> 4) * 16 + (c >> 2)) * 4 + (c & 3)) * 128 + (r & 15) * 8;
      *(uint4*)(As + dst) = v;
    }
  }
  barrier_lds();

  float h[4][4][4];          // fp32 ODE state, MFMA C-layout
  unsigned int ks[4][4][2];  // RK4 ksum, packed bf16 pairs
#pragma unroll
  for (int mt = 0; mt < 4; ++mt)
#pragma unroll
    for (int ni = 0; ni < 4; ++ni) {
      ks[mt][ni][0] = 0u; ks[mt][ni][1] = 0u;
      int n = (4 * wv + ni) * 16 + ml;
#pragma unroll
      for (int r = 0; r < 4; ++r) h[mt][ni][r] = bf2f(As[a_addr(mt * 16 + 4 * qd + r, n)]);
    }

  for (int e = 0; e < 16; ++e) {  // 4 RK4 steps x 4 stages
    int stg = e & 3;
    float tval = 0.25f * (float)(e >> 2) + ((stg == 3) ? 0.25f : (stg ? 0.125f : 0.f));
    floatx4 acc[4][4];
    gemm64d(W1t, W2t, As, wv, lane, bb, acc);
    ln_epi64(acc, As, Ps, 0, 2, 3, true, tval, wv, lane, tid, red, stat);
    gemm64d(W2t, Wot, As, wv, lane, bb, acc);
    ln_epi64(acc, As, Ps, 4, 5, 6, false, 0.f, wv, lane, tid, red, stat);
    gemm64d(Wot, W1t, As, wv, lane, bb, acc);  // preloads next eval's W1
    stage_epi64(acc, h, ks, As, Ps, stg, wv, lane);
  }

  // final h_ode (bf16, row-major) for the GRU phase
#pragma unroll
  for (int mt = 0; mt < 4; ++mt)
#pragma unroll
    for (int ni = 0; ni < 4; ++ni)
#pragma unroll
      for (int r = 0; r < 4; ++r) {
        size_t row = m0 + mt * 16 + 4 * qd + r;
        int n = (4 * wv + ni) * 16 + ml;
        Yout[row * 512 + n] = f2bf(h[mt][ni][r]);
      }
}

// ---------------------------------------------------------------------------
// GRU step (unchanged): gi = y_t @ W_ih, gh = h_prev @ W_hh, gates.
// grid (32, 8): 32 rows x 64 gate-cols per block, 4 waves.
// ---------------------------------------------------------------------------
__global__ __launch_bounds__(256) void gru_step(
    const unsigned short* __restrict__ Yt, const float* __restrict__ hprev,
    float* __restrict__ hnew, const unsigned short* __restrict__ Wiht,
    const unsigned short* __restrict__ Whht, const float* __restrict__ bih,
    const float* __restrict__ bhh) {
  __shared__ __align__(16) unsigned short Ay[32 * BP];
  __shared__ __align__(16) unsigned short Ah[32 * BP];
  __shared__ __align__(16) unsigned short Bg[6 * 64 * BP];
  const int tid = threadIdx.x, lane = tid & 63, wv = tid >> 6;
  const int ml = lane & 15, qd = lane >> 4;
  const int m0 = blockIdx.x * 32;
  const int j0 = blockIdx.y * 64;

  floatx4 acc[2][6];
#pragma unroll
  for (int mi = 0; mi < 2; ++mi)
#pragma unroll
    for (int g = 0; g < 6; ++g) acc[mi][g] = 0.f;

  for (int kk = 0; kk < 16; ++kk) {
    __syncthreads();
#pragma unroll
    for (int c = 0; c < 7; ++c) {
      int id = c * 256 + tid;
      if (id < 128) {
        int r = id >> 2, kc = id & 3;
        *(uint4*)(Ay + r * BP + kc * 8) =
            *(const uint4*)(Yt + (size_t)(m0 + r) * 512 + kk * 32 + kc * 8);
      } else if (id < 256) {
        int id2 = id - 128;
        int r = id2 >> 2, kc = id2 & 3;
        const float* s = hprev + (size_t)(m0 + r) * 512 + kk * 32 + kc * 8;
        unsigned short o[8] __attribute__((aligned(16)));
#pragma unroll
        for (int j = 0; j < 8; ++j) o[j] = f2bf(s[j]);
        *(uint4*)(Ah + r * BP + kc * 8) = *(const uint4*)o;
      } else {
        int id2 = id - 256;
        int g = id2 >> 8;
        int rem = id2 & 255;
        int r = rem >> 2, kc = rem & 3;
        const unsigned short* mat = (g < 3) ? Wiht : Whht;
        int gate = (g < 3) ? g : (g - 3);
        *(uint4*)(Bg + g * (64 * BP) + r * BP + kc * 8) =
            *(const uint4*)(mat + (size_t)(gate * 512 + j0 + r) * 512 + kk * 32 + kc * 8);
      }
    }
    __syncthreads();
    bf16x8 ay[2], ah[2];
#pragma unroll
    for (int mi = 0; mi < 2; ++mi) {
      ay[mi] = *(const bf16x8*)&Ay[(16 * mi + ml) * BP + qd * 8];
      ah[mi] = *(const bf16x8*)&Ah[(16 * mi + ml) * BP + qd * 8];
    }
#pragma unroll
    for (int g = 0; g < 6; ++g) {
      bf16x8 b = *(const bf16x8*)&Bg[g * (64 * BP) + (16 * wv + ml) * BP + qd * 8];
#pragma unroll
      for (int mi = 0; mi < 2; ++mi)
        acc[mi][g] = __builtin_amdgcn_mfma_f32_16x16x32_bf16((g < 3) ? ay[mi] : ah[mi], b,
                                                             acc[mi][g], 0, 0, 0);
    }
  }
  int j = j0 + 16 * wv + ml;
  float bi_r = bih[j], bi_z = bih[512 + j], bi_n = bih[1024 + j];
  float bh_r = bhh[j], bh_z = bhh[512 + j], bh_n = bhh[1024 + j];
#pragma unroll
  for (int mi = 0; mi < 2; ++mi)
#pragma unroll
    for (int r = 0; r < 4; ++r) {
      size_t row = (size_t)(m0 + 16 * mi + 4 * qd + r);
      float rg = acc[mi][0][r] + bi_r + acc[mi][3][r] + bh_r;
      rg = 1.f / (1.f + __expf(-rg));
      float zg = acc[mi][1][r] + bi_z + acc[mi][4][r] + bh_z;
      zg = 1.f / (1.f + __expf(-zg));
      float ng = tanhf(acc[mi][2][r] + bi_n + rg * (acc[mi][5][r] + bh_n));
      float hp = hprev[row * 512 + j];
      hnew[row * 512 + j] = (1.f - zg) * ng + zg * hp;
    }
}

__global__ void zero_h(float* hf) {
  int i = blockIdx.x * 256 + threadIdx.x;
  hf[i] = 0.f;
}

// ---------------------------------------------------------------------------
extern "C" void kernel_launch(void* const* d_in, const int* in_sizes, int n_in,
                              void* d_out, int out_size, void* d_ws, size_t ws_size,
                              hipStream_t stream) {
  (void)in_sizes; (void)n_in; (void)out_size; (void)ws_size;
  const float* xs    = (const float*)d_in[0];
  const float* obsW  = (const float*)d_in[1];
  const float* obsb  = (const float*)d_in[2];
  const float* obsg  = (const float*)d_in[3];
  const float* obsbe = (const float*)d_in[4];
  const float* W1    = (const float*)d_in[5];
  const float* b1    = (const float*)d_in[6];
  const float* g1    = (const float*)d_in[7];
  const float* be1   = (const float*)d_in[8];
  const float* W2    = (const float*)d_in[9];
  const float* b2    = (const float*)d_in[10];
  const float* g2    = (const float*)d_in[11];
  const float* be2   = (const float*)d_in[12];
  const float* Wo    = (const float*)d_in[13];
  const float* bo    = (const float*)d_in[14];
  const float* Wih   = (const float*)d_in[15];
  const float* bih   = (const float*)d_in[16];
  const float* Whh   = (const float*)d_in[17];
  const float* bhh   = (const float*)d_in[18];

  char* p = (char*)d_ws;
  auto take = [&](size_t bytes) { char* q = p; p += (bytes + 255) & ~(size_t)255; return q; };
  unsigned short* W1t  = (unsigned short*)take((size_t)512 * 512 * 2);
  unsigned short* W2t  = (unsigned short*)take((size_t)512 * 512 * 2);
  unsigned short* Wot  = (unsigned short*)take((size_t)512 * 512 * 2);
  unsigned short* Wiht = (unsigned short*)take((size_t)1536 * 512 * 2);
  unsigned short* Whht = (unsigned short*)take((size_t)1536 * 512 * 2);
  float* hf0 = (float*)take((size_t)1024 * 512 * 4);
  float* hf1 = (float*)take((size_t)1024 * 512 * 4);
  unsigned short* Yb = (unsigned short*)take((size_t)65536 * 512 * 2);

  dim3 tb(32, 8);
  tile_weight<<<128, 256, 0, stream>>>(W1, W1t);  // first 512 of 513 rows
  tile_weight<<<128, 256, 0, stream>>>(W2, W2t);
  tile_weight<<<128, 256, 0, stream>>>(Wo, Wot);
  transpose_f2b<<<dim3(48, 16), tb, 0, stream>>>(Wih, Wiht, 512, 1536);
  transpose_f2b<<<dim3(48, 16), tb, 0, stream>>>(Whh, Whht, 512, 1536);

  obs_embed<<<16384, 256, 0, stream>>>(xs, obsW, obsb, obsg, obsbe, Yb);

  // tr = W1 row 512 (time row), folded into layer-1 bias per eval.
  ode_mega<<<1024, 512, 0, stream>>>(Yb, W1t, W2t, Wot, b1, W1 + 512 * 512, g1, be1, b2, g2,
                                     be2, bo, Yb);

  zero_h<<<2048, 256, 0, stream>>>(hf0);
  float* hf[2] = {hf0, hf1};
  for (int t = 0; t < 64; ++t) {
    int s = t & 1, d = s ^ 1;
    float* hn = (t == 63) ? (float*)d_out : hf[d];
    gru_step<<<dim3(32, 8), 256, 0, stream>>>(Yb + (size_t)t * 1024 * 512, hf[s], hn, Wiht, Whht,
                                              bih, bhh);
  }
}